// Round 1
// baseline (2502.063 us; speedup 1.0000x reference)
//
#include <hip/hip_runtime.h>
#include <stdint.h>
#include <stddef.h>

typedef unsigned short u16;
typedef __attribute__((ext_vector_type(8))) short bf16x8;   // 8 bf16 in 4 VGPRs
typedef __attribute__((ext_vector_type(4))) float f32x4;
typedef __attribute__((ext_vector_type(4))) unsigned short u16x4;

#define TC 768
#define TT 2560
#define NB 2
#define NM (NB * TT)   // 5120 rows
#define NH 12
#define HD 64
#define NL 6

static __device__ __forceinline__ u16 f2bf(float f) {
  unsigned u = __builtin_bit_cast(unsigned, f);
  return (u16)((u + 0x7FFFu + ((u >> 16) & 1u)) >> 16);  // RTNE
}

// ---------------- embed: x = concat(tokens) + pos ----------------
__global__ __launch_bounds__(256) void embed_kernel(
    const float* __restrict__ cm, const float* __restrict__ cu, const float* __restrict__ cd,
    const float* __restrict__ cl, const float* __restrict__ cr,
    const float* __restrict__ iu, const float* __restrict__ id_, const float* __restrict__ il,
    const float* __restrict__ ir, const float* __restrict__ it,
    const float* __restrict__ pos, float* __restrict__ x)
{
  int v = blockIdx.x * 256 + threadIdx.x;
  const int NV = NM * TC / 4;
  if (v >= NV) return;
  int e = v * 4;
  int b = e / (TT * TC);
  int rem = e - b * (TT * TC);
  int tpos = rem / TC;
  int c = rem - tpos * TC;
  int s = tpos >> 8;
  int tt = tpos & 255;
  const float* src;
  switch (s) {
    case 0: src = cm; break; case 1: src = cu; break; case 2: src = cd; break;
    case 3: src = cl; break; case 4: src = cr; break; case 5: src = iu; break;
    case 6: src = id_; break; case 7: src = il; break; case 8: src = ir; break;
    default: src = it; break;
  }
  f32x4 a = *(const f32x4*)&src[(size_t)(b * 256 + tt) * TC + c];
  f32x4 p = *(const f32x4*)&pos[(size_t)tpos * TC + c];
  *(f32x4*)&x[e] = a + p;
}

// ---------------- fp32 -> bf16 convert ----------------
__global__ __launch_bounds__(256) void conv_kernel(const float* __restrict__ in,
                                                   u16* __restrict__ out, int n4)
{
  int v = blockIdx.x * 256 + threadIdx.x;
  if (v >= n4) return;
  f32x4 f = *(const f32x4*)&in[(size_t)v * 4];
  u16x4 r;
  r[0] = f2bf(f[0]); r[1] = f2bf(f[1]); r[2] = f2bf(f[2]); r[3] = f2bf(f[3]);
  *(u16x4*)&out[(size_t)v * 4] = r;
}

// ---------------- LayerNorm (row per block) -> bf16 ----------------
__global__ __launch_bounds__(256) void ln_kernel(
    const float* __restrict__ x, const float* __restrict__ w, const float* __restrict__ bb,
    u16* __restrict__ out)
{
  int row = blockIdx.x;
  int tid = threadIdx.x;
  const float* xr = x + (size_t)row * TC;
  float v0 = xr[tid], v1 = xr[tid + 256], v2 = xr[tid + 512];
  float s = v0 + v1 + v2;
  float ss = v0 * v0 + v1 * v1 + v2 * v2;
  #pragma unroll
  for (int m = 1; m < 64; m <<= 1) { s += __shfl_xor(s, m, 64); ss += __shfl_xor(ss, m, 64); }
  __shared__ float red[8];
  int wave = tid >> 6, lane = tid & 63;
  if (lane == 0) { red[wave] = s; red[4 + wave] = ss; }
  __syncthreads();
  s = red[0] + red[1] + red[2] + red[3];
  ss = red[4] + red[5] + red[6] + red[7];
  const float inv = 1.0f / 768.0f;
  float mu = s * inv;
  float var = ss * inv - mu * mu;
  float rs = rsqrtf(var + 1e-5f);
  size_t o = (size_t)row * TC + tid;
  out[o]       = f2bf((v0 - mu) * rs * w[tid]       + bb[tid]);
  out[o + 256] = f2bf((v1 - mu) * rs * w[tid + 256] + bb[tid + 256]);
  out[o + 512] = f2bf((v2 - mu) * rs * w[tid + 512] + bb[tid + 512]);
}

// ---------------- GEMM body: C[M,N] = A[M,K] @ Bw[N,K]^T + bias ----------------
// 128x128 tile, BK=32, 4 waves each owning 64x64. EPI: 0=bf16 store, 1=gelu->bf16, 2=fp32 resid +=
template<int EPI>
static __device__ __forceinline__ void gemm_body(
    const u16* __restrict__ A, const u16* __restrict__ Bw,
    const float* __restrict__ bias, u16* __restrict__ outb,
    float* __restrict__ resid, int K, int N)
{
  const int PAD = 40;                       // 80B row stride: breaks 8-way read conflict
  __shared__ u16 As[128 * 40];
  __shared__ u16 Bs[128 * 40];
  const int bm = blockIdx.x, bn = blockIdx.y;
  const int tid = threadIdx.x;
  const int wave = tid >> 6, lane = tid & 63;
  const int wr = wave >> 1, wc = wave & 1;
  const int l15 = lane & 15, l16 = lane >> 4;

  f32x4 acc[4][4];
  #pragma unroll
  for (int m = 0; m < 4; ++m)
    #pragma unroll
    for (int n = 0; n < 4; ++n) acc[m][n] = f32x4{0.f, 0.f, 0.f, 0.f};

  const int arow = tid >> 2;                // 0..63
  const int kcol = (tid & 3) * 8;           // 0,8,16,24
  const size_t abase = (size_t)(bm * 128 + arow) * K + kcol;
  const size_t bbase = (size_t)(bn * 128 + arow) * K + kcol;
  const int nk = K >> 5;

  for (int kt = 0; kt < nk; ++kt) {
    bf16x8 a0 = *(const bf16x8*)&A[abase + (size_t)kt * 32];
    bf16x8 a1 = *(const bf16x8*)&A[abase + (size_t)64 * K + (size_t)kt * 32];
    bf16x8 b0 = *(const bf16x8*)&Bw[bbase + (size_t)kt * 32];
    bf16x8 b1 = *(const bf16x8*)&Bw[bbase + (size_t)64 * K + (size_t)kt * 32];
    *(bf16x8*)&As[arow * PAD + kcol] = a0;
    *(bf16x8*)&As[(arow + 64) * PAD + kcol] = a1;
    *(bf16x8*)&Bs[arow * PAD + kcol] = b0;
    *(bf16x8*)&Bs[(arow + 64) * PAD + kcol] = b1;
    __syncthreads();
    bf16x8 aF[4], bF[4];
    #pragma unroll
    for (int m = 0; m < 4; ++m) aF[m] = *(const bf16x8*)&As[(wr * 64 + m * 16 + l15) * PAD + l16 * 8];
    #pragma unroll
    for (int n = 0; n < 4; ++n) bF[n] = *(const bf16x8*)&Bs[(wc * 64 + n * 16 + l15) * PAD + l16 * 8];
    #pragma unroll
    for (int m = 0; m < 4; ++m)
      #pragma unroll
      for (int n = 0; n < 4; ++n)
        acc[m][n] = __builtin_amdgcn_mfma_f32_16x16x32_bf16(aF[m], bF[n], acc[m][n], 0, 0, 0);
    __syncthreads();
  }

  #pragma unroll
  for (int m = 0; m < 4; ++m) {
    int row = bm * 128 + wr * 64 + m * 16 + l16 * 4;
    #pragma unroll
    for (int n = 0; n < 4; ++n) {
      int col = bn * 128 + wc * 64 + n * 16 + l15;
      float bv = bias[col];
      #pragma unroll
      for (int r = 0; r < 4; ++r) {
        float v = acc[m][n][r] + bv;
        size_t off = (size_t)(row + r) * N + col;
        if (EPI == 0) {
          outb[off] = f2bf(v);
        } else if (EPI == 1) {
          float g = 0.5f * v * (1.0f + erff(v * 0.70710678118654752f));  // exact GELU
          outb[off] = f2bf(g);
        } else {
          resid[off] += v;
        }
      }
    }
  }
}

template<int EPI>
__global__ __launch_bounds__(256) void gemm_kernel(
    const u16* __restrict__ A, const u16* __restrict__ Bw,
    const float* __restrict__ bias, u16* __restrict__ outb,
    float* __restrict__ resid, int K, int N)
{
  gemm_body<EPI>(A, Bw, bias, outb, resid, K, N);
}

// fused QKV: blockIdx.z selects which projection (keeps 720 blocks in flight)
__global__ __launch_bounds__(256) void gemm_qkv_kernel(
    const u16* __restrict__ A,
    const u16* __restrict__ Bq, const u16* __restrict__ Bk, const u16* __restrict__ Bv,
    const float* __restrict__ bq, const float* __restrict__ bk, const float* __restrict__ bv,
    u16* __restrict__ oq, u16* __restrict__ ok, u16* __restrict__ ov, int K, int N)
{
  const u16* Bw; const float* bias; u16* outb;
  if (blockIdx.z == 0)      { Bw = Bq; bias = bq; outb = oq; }
  else if (blockIdx.z == 1) { Bw = Bk; bias = bk; outb = ok; }
  else                      { Bw = Bv; bias = bv; outb = ov; }
  gemm_body<0>(A, Bw, bias, outb, nullptr, K, N);
}

// ---------------- flash attention with tiled block-causal mask ----------------
// grid (40 q-tiles, B*H). block = 4 waves; wave owns 16 q rows. k-tiles of 64.
// mask[i][j] = (j%256) <= (i%256): tile skip if kpos0>qpos0, triangular if ==.
__global__ __launch_bounds__(256) void attn_kernel(
    const u16* __restrict__ qb, const u16* __restrict__ kb,
    const u16* __restrict__ vb, u16* __restrict__ yb)
{
  __shared__ u16 Ks[64 * 72];        // [key][hd], padded
  __shared__ u16 Vt[64 * 72];        // [hd][key], padded (transposed V)
  __shared__ u16 Ps[4 * 16 * 72];    // per-wave P buffer [16 q][64 key], padded
  const int qt = blockIdx.x;
  const int bh = blockIdx.y;
  const int b = bh / NH, h = bh - (bh / NH) * NH;
  const int tid = threadIdx.x;
  const int wave = tid >> 6, lane = tid & 63;
  const int l15 = lane & 15, l16 = lane >> 4;
  const size_t base = (size_t)b * TT * TC + (size_t)h * HD;
  const int q0 = qt * 64;
  const int qpos0 = q0 & 255;

  bf16x8 qA0, qA1;
  {
    int qrow = q0 + wave * 16 + l15;
    qA0 = *(const bf16x8*)&qb[base + (size_t)qrow * TC + l16 * 8];
    qA1 = *(const bf16x8*)&qb[base + (size_t)qrow * TC + 32 + l16 * 8];
  }
  f32x4 o[4];
  #pragma unroll
  for (int n = 0; n < 4; ++n) o[n] = f32x4{0.f, 0.f, 0.f, 0.f};
  float mrow[4] = {-1e30f, -1e30f, -1e30f, -1e30f};
  float lrow[4] = {0.f, 0.f, 0.f, 0.f};

  const int st = tid >> 3;           // 0..31 staging row
  const int sd = (tid & 7) * 8;      // 0..56 staging col
  u16* psw = &Ps[wave * 16 * 72];

  for (int kt = 0; kt < TT / 64; ++kt) {
    int kpos0 = (kt * 64) & 255;
    if (kpos0 > qpos0) continue;     // fully masked tile (block-uniform)
    __syncthreads();                 // protect prior iter's LDS reads
    #pragma unroll
    for (int i = 0; i < 2; ++i) {
      int t = st + i * 32;
      bf16x8 kv = *(const bf16x8*)&kb[base + (size_t)(kt * 64 + t) * TC + sd];
      *(bf16x8*)&Ks[t * 72 + sd] = kv;
      bf16x8 vv = *(const bf16x8*)&vb[base + (size_t)(kt * 64 + t) * TC + sd];
      #pragma unroll
      for (int j = 0; j < 8; ++j) {
        int jj = (j + (sd >> 3)) & 7;            // swizzle write order: spread banks
        Vt[(sd + jj) * 72 + t] = ((const u16*)&vv)[jj];
      }
    }
    __syncthreads();

    // S = q @ k^T   (16q x 64k per wave)
    f32x4 s[4];
    #pragma unroll
    for (int c = 0; c < 4; ++c) {
      bf16x8 k0 = *(const bf16x8*)&Ks[(c * 16 + l15) * 72 + l16 * 8];
      bf16x8 k1 = *(const bf16x8*)&Ks[(c * 16 + l15) * 72 + 32 + l16 * 8];
      f32x4 z = f32x4{0.f, 0.f, 0.f, 0.f};
      z = __builtin_amdgcn_mfma_f32_16x16x32_bf16(qA0, k0, z, 0, 0, 0);
      s[c] = __builtin_amdgcn_mfma_f32_16x16x32_bf16(qA1, k1, z, 0, 0, 0);
    }
    const bool diag = (kpos0 == qpos0);
    #pragma unroll
    for (int c = 0; c < 4; ++c)
      #pragma unroll
      for (int r = 0; r < 4; ++r) {
        float sv = s[c][r] * 0.125f;             // 1/sqrt(64)
        if (diag && (c * 16 + l15) > (wave * 16 + l16 * 4 + r)) sv = -1e30f;
        s[c][r] = sv;
      }

    // online softmax per q-row (rows live on 16-lane groups)
    #pragma unroll
    for (int r = 0; r < 4; ++r) {
      float t = fmaxf(fmaxf(s[0][r], s[1][r]), fmaxf(s[2][r], s[3][r]));
      t = fmaxf(t, __shfl_xor(t, 1, 64));
      t = fmaxf(t, __shfl_xor(t, 2, 64));
      t = fmaxf(t, __shfl_xor(t, 4, 64));
      t = fmaxf(t, __shfl_xor(t, 8, 64));
      float mnew = fmaxf(mrow[r], t);
      float sf = __expf(mrow[r] - mnew);
      mrow[r] = mnew;
      lrow[r] *= sf;
      #pragma unroll
      for (int n = 0; n < 4; ++n) o[n][r] *= sf;
      float ts = 0.f;
      #pragma unroll
      for (int c = 0; c < 4; ++c) {
        float p = __expf(s[c][r] - mnew);        // masked -> exp(-huge) = 0
        s[c][r] = p;
        ts += p;
      }
      ts += __shfl_xor(ts, 1, 64);
      ts += __shfl_xor(ts, 2, 64);
      ts += __shfl_xor(ts, 4, 64);
      ts += __shfl_xor(ts, 8, 64);
      lrow[r] += ts;
      #pragma unroll
      for (int c = 0; c < 4; ++c)
        psw[(l16 * 4 + r) * 72 + c * 16 + l15] = f2bf(s[c][r]);
    }

    // O += P @ V  (contract over 64 keys)
    bf16x8 pA0 = *(const bf16x8*)&psw[l15 * 72 + l16 * 8];
    bf16x8 pA1 = *(const bf16x8*)&psw[l15 * 72 + 32 + l16 * 8];
    #pragma unroll
    for (int n = 0; n < 4; ++n) {
      bf16x8 v0 = *(const bf16x8*)&Vt[(n * 16 + l15) * 72 + l16 * 8];
      bf16x8 v1 = *(const bf16x8*)&Vt[(n * 16 + l15) * 72 + 32 + l16 * 8];
      o[n] = __builtin_amdgcn_mfma_f32_16x16x32_bf16(pA0, v0, o[n], 0, 0, 0);
      o[n] = __builtin_amdgcn_mfma_f32_16x16x32_bf16(pA1, v1, o[n], 0, 0, 0);
    }
  }

  #pragma unroll
  for (int r = 0; r < 4; ++r) {
    float invl = 1.0f / lrow[r];
    int row = q0 + wave * 16 + l16 * 4 + r;
    #pragma unroll
    for (int n = 0; n < 4; ++n) {
      int col = h * HD + n * 16 + l15;
      yb[(size_t)(b * TT + row) * TC + col] = f2bf(o[n][r] * invl);
    }
  }
}

// ---------------- host ----------------
extern "C" void kernel_launch(void* const* d_in, const int* in_sizes, int n_in,
                              void* d_out, int out_size, void* d_ws, size_t ws_size,
                              hipStream_t stream)
{
  (void)in_sizes; (void)n_in; (void)out_size; (void)ws_size;
  const float* IU = (const float*)d_in[0];
  const float* ID = (const float*)d_in[1];
  const float* IL = (const float*)d_in[2];
  const float* IR = (const float*)d_in[3];
  const float* IT = (const float*)d_in[4];
  const float* CM = (const float*)d_in[5];
  const float* CU = (const float*)d_in[6];
  const float* CD = (const float*)d_in[7];
  const float* CL = (const float*)d_in[8];
  const float* CR = (const float*)d_in[9];
  const float* POS = (const float*)d_in[10];
  const float* LN1W = (const float*)d_in[11];
  const float* LN1B = (const float*)d_in[12];
  const float* LN2W = (const float*)d_in[13];
  const float* LN2B = (const float*)d_in[14];
  const float* WQ = (const float*)d_in[15];
  const float* WK = (const float*)d_in[16];
  const float* WV = (const float*)d_in[17];
  const float* WP = (const float*)d_in[18];
  const float* BQ = (const float*)d_in[19];
  const float* BK = (const float*)d_in[20];
  const float* BV = (const float*)d_in[21];
  const float* BP = (const float*)d_in[22];
  const float* W1 = (const float*)d_in[23];
  const float* B1 = (const float*)d_in[24];
  const float* W2 = (const float*)d_in[25];
  const float* B2 = (const float*)d_in[26];

  float* x = (float*)d_out;
  char* ws = (char*)d_ws;
  // ws layout (bytes): per-layer bf16 weight slots, then activations. ~53.5 MB total.
  u16* ws_wq = (u16*)(ws + 0);
  u16* ws_wk = (u16*)(ws + 1179648);
  u16* ws_wv = (u16*)(ws + 2359296);
  u16* ws_wp = (u16*)(ws + 3538944);
  u16* ws_w1 = (u16*)(ws + 4718592);
  u16* ws_w2 = (u16*)(ws + 9437184);
  u16* ws_h  = (u16*)(ws + 14155776);
  u16* ws_q  = (u16*)(ws + 22020096);
  u16* ws_k  = (u16*)(ws + 29884416);
  u16* ws_v  = (u16*)(ws + 37748736);
  u16* ws_y  = (u16*)(ws + 45613056);
  u16* ws_g  = ws_q;   // [5120,3072] aliases q/k/v/y (dead by MLP1)

  embed_kernel<<<(NM * TC / 4) / 256, 256, 0, stream>>>(CM, CU, CD, CL, CR, IU, ID, IL, IR, IT, POS, x);

  const int WSL = 768 * 768;       // per-layer square weight elems
  const int W1SL = 3072 * 768;
  for (int li = 0; li < NL; ++li) {
    conv_kernel<<<WSL / 4 / 256, 256, 0, stream>>>(WQ + (size_t)li * WSL, ws_wq, WSL / 4);
    conv_kernel<<<WSL / 4 / 256, 256, 0, stream>>>(WK + (size_t)li * WSL, ws_wk, WSL / 4);
    conv_kernel<<<WSL / 4 / 256, 256, 0, stream>>>(WV + (size_t)li * WSL, ws_wv, WSL / 4);
    conv_kernel<<<WSL / 4 / 256, 256, 0, stream>>>(WP + (size_t)li * WSL, ws_wp, WSL / 4);
    conv_kernel<<<W1SL / 4 / 256, 256, 0, stream>>>(W1 + (size_t)li * W1SL, ws_w1, W1SL / 4);
    conv_kernel<<<W1SL / 4 / 256, 256, 0, stream>>>(W2 + (size_t)li * W1SL, ws_w2, W1SL / 4);

    ln_kernel<<<NM, 256, 0, stream>>>(x, LN1W + li * TC, LN1B + li * TC, ws_h);
    gemm_qkv_kernel<<<dim3(NM / 128, TC / 128, 3), 256, 0, stream>>>(
        ws_h, ws_wq, ws_wk, ws_wv, BQ + li * TC, BK + li * TC, BV + li * TC,
        ws_q, ws_k, ws_v, TC, TC);
    attn_kernel<<<dim3(TT / 64, NB * NH), 256, 0, stream>>>(ws_q, ws_k, ws_v, ws_y);
    gemm_kernel<2><<<dim3(NM / 128, TC / 128), 256, 0, stream>>>(
        ws_y, ws_wp, BP + li * TC, nullptr, x, TC, TC);
    ln_kernel<<<NM, 256, 0, stream>>>(x, LN2W + li * TC, LN2B + li * TC, ws_h);
    gemm_kernel<1><<<dim3(NM / 128, 3072 / 128), 256, 0, stream>>>(
        ws_h, ws_w1, B1 + (size_t)li * 3072, ws_g, nullptr, TC, 3072);
    gemm_kernel<2><<<dim3(NM / 128, TC / 128), 256, 0, stream>>>(
        ws_g, ws_w2, B2 + li * TC, nullptr, x, 3072, TC);
  }
}

// Round 2
// 2289.135 us; speedup vs baseline: 1.0930x; 1.0930x over previous
//
#include <hip/hip_runtime.h>
#include <stdint.h>
#include <stddef.h>

typedef unsigned short u16;
typedef __attribute__((ext_vector_type(8))) short bf16x8;   // 8 bf16 in 4 VGPRs
typedef __attribute__((ext_vector_type(4))) float f32x4;
typedef __attribute__((ext_vector_type(4))) unsigned short u16x4;

#define TC 768
#define TT 2560
#define NB 2
#define NM (NB * TT)   // 5120 rows
#define NH 12
#define HD 64
#define NL 6
#define LDQ 2304       // fused qkv row stride

static __device__ __forceinline__ u16 f2bf(float f) {
  unsigned u = __builtin_bit_cast(unsigned, f);
  return (u16)((u + 0x7FFFu + ((u >> 16) & 1u)) >> 16);  // RTNE
}

// async global->LDS, 16B per lane. LDS dest is wave-uniform base + lane*16;
// our per-lane lds ptr is constructed to equal exactly that.
static __device__ __forceinline__ void gload16(const void* g, void* l) {
  __builtin_amdgcn_global_load_lds((const __attribute__((address_space(1))) void*)g,
                                   (__attribute__((address_space(3))) void*)l, 16, 0, 0);
}

// ---------------- embed: x = concat(tokens) + pos ----------------
__global__ __launch_bounds__(256) void embed_kernel(
    const float* __restrict__ cm, const float* __restrict__ cu, const float* __restrict__ cd,
    const float* __restrict__ cl, const float* __restrict__ cr,
    const float* __restrict__ iu, const float* __restrict__ id_, const float* __restrict__ il,
    const float* __restrict__ ir, const float* __restrict__ it,
    const float* __restrict__ pos, float* __restrict__ x)
{
  int v = blockIdx.x * 256 + threadIdx.x;
  const int NV = NM * TC / 4;
  if (v >= NV) return;
  int e = v * 4;
  int b = e / (TT * TC);
  int rem = e - b * (TT * TC);
  int tpos = rem / TC;
  int c = rem - tpos * TC;
  int s = tpos >> 8;
  int tt = tpos & 255;
  const float* src;
  switch (s) {
    case 0: src = cm; break; case 1: src = cu; break; case 2: src = cd; break;
    case 3: src = cl; break; case 4: src = cr; break; case 5: src = iu; break;
    case 6: src = id_; break; case 7: src = il; break; case 8: src = ir; break;
    default: src = it; break;
  }
  f32x4 a = *(const f32x4*)&src[(size_t)(b * 256 + tt) * TC + c];
  f32x4 p = *(const f32x4*)&pos[(size_t)tpos * TC + c];
  *(f32x4*)&x[e] = a + p;
}

// ---------------- per-layer weight convert: Wq,Wk,Wv -> wqkv; Wp; W1; W2 ----------------
__global__ __launch_bounds__(256) void conv_all_kernel(
    const float* __restrict__ Wq, const float* __restrict__ Wk, const float* __restrict__ Wv,
    const float* __restrict__ Wp, const float* __restrict__ W1, const float* __restrict__ W2,
    u16* __restrict__ wqkv, u16* __restrict__ wp, u16* __restrict__ w1, u16* __restrict__ w2)
{
  const int SQ = 768 * 768;          // 589824
  int v = blockIdx.x * 256 + threadIdx.x;   // vec4 index; total 1,769,472
  int e = v * 4;
  const float* src; u16* dst;
  if (e < 3 * SQ) {
    int wsel = e / SQ; int le = e - wsel * SQ;
    src = (wsel == 0 ? Wq : wsel == 1 ? Wk : Wv) + le;
    dst = wqkv + e;
  } else if (e < 4 * SQ) {
    src = Wp + (e - 3 * SQ); dst = wp + (e - 3 * SQ);
  } else if (e < 8 * SQ) {
    src = W1 + (e - 4 * SQ); dst = w1 + (e - 4 * SQ);
  } else {
    src = W2 + (e - 8 * SQ); dst = w2 + (e - 8 * SQ);
  }
  f32x4 f = *(const f32x4*)src;
  u16x4 r;
  r[0] = f2bf(f[0]); r[1] = f2bf(f[1]); r[2] = f2bf(f[2]); r[3] = f2bf(f[3]);
  *(u16x4*)dst = r;
}

// ---------------- LayerNorm (row per block) -> bf16 ----------------
__global__ __launch_bounds__(256) void ln_kernel(
    const float* __restrict__ x, const float* __restrict__ w, const float* __restrict__ bb,
    u16* __restrict__ out)
{
  int row = blockIdx.x;
  int tid = threadIdx.x;
  const float* xr = x + (size_t)row * TC;
  float v0 = xr[tid], v1 = xr[tid + 256], v2 = xr[tid + 512];
  float s = v0 + v1 + v2;
  float ss = v0 * v0 + v1 * v1 + v2 * v2;
  #pragma unroll
  for (int m = 1; m < 64; m <<= 1) { s += __shfl_xor(s, m, 64); ss += __shfl_xor(ss, m, 64); }
  __shared__ float red[8];
  int wave = tid >> 6, lane = tid & 63;
  if (lane == 0) { red[wave] = s; red[4 + wave] = ss; }
  __syncthreads();
  s = red[0] + red[1] + red[2] + red[3];
  ss = red[4] + red[5] + red[6] + red[7];
  const float inv = 1.0f / 768.0f;
  float mu = s * inv;
  float var = ss * inv - mu * mu;
  float rs = rsqrtf(var + 1e-5f);
  size_t o = (size_t)row * TC + tid;
  out[o]       = f2bf((v0 - mu) * rs * w[tid]       + bb[tid]);
  out[o + 256] = f2bf((v1 - mu) * rs * w[tid + 256] + bb[tid + 256]);
  out[o + 512] = f2bf((v2 - mu) * rs * w[tid + 512] + bb[tid + 512]);
}

// ---------------- GEMM: C[M,N] = A[M,K] @ Bw[N,K]^T + bias ----------------
// m97 structure: linear LDS + global_load_lds(16B), 2-barrier K loop.
// TM=128: 4 waves as 2x2, wave tile 64x64 (acc 4x4). TM=64: 4 waves as 1x4, wave tile 64x32 (acc 4x2).
// EPI: 0 = QKV bf16 store w/ 3-section bias; 1 = GELU->bf16; 2 = fp32 residual +=
template<int EPI, int TM>
__global__ __launch_bounds__(256) void gemm_kernel(
    const u16* __restrict__ A, const u16* __restrict__ Bw,
    const float* __restrict__ b0, const float* __restrict__ b1, const float* __restrict__ b2,
    u16* __restrict__ outb, float* __restrict__ resid, int K, int N)
{
  constexpr int NR = (TM == 128) ? 4 : 2;
  __shared__ __align__(16) u16 As[TM * 32];
  __shared__ __align__(16) u16 Bs[128 * 32];
  const int bm = blockIdx.x, bn = blockIdx.y;
  const int tid = threadIdx.x;
  const int wave = tid >> 6;
  const int lane = tid & 63;
  const int wr = (TM == 128) ? (wave >> 1) : 0;
  const int wc = (TM == 128) ? (wave & 1) : wave;
  const int WCS = (TM == 128) ? 64 : 32;
  const int l15 = lane & 15, l16 = lane >> 4;

  f32x4 acc[4][NR];
  #pragma unroll
  for (int m = 0; m < 4; ++m)
    #pragma unroll
    for (int n = 0; n < NR; ++n) acc[m][n] = f32x4{0.f, 0.f, 0.f, 0.f};

  const int srow = tid >> 2;                // 0..63
  const int scol = (tid & 3) * 8;           // 0,8,16,24
  const u16* gA = A + (size_t)(bm * TM + srow) * K + scol;
  const u16* gB = Bw + (size_t)(bn * 128 + srow) * K + scol;
  u16* lA = &As[srow * 32 + scol];          // per-lane == wave base + lane*16B
  u16* lB = &Bs[srow * 32 + scol];
  const int nkt = K >> 5;

  for (int kt = 0; kt < nkt; ++kt) {
    size_t go = (size_t)kt * 32;
    gload16(gA + go, lA);
    if (TM == 128) gload16(gA + go + (size_t)64 * K, lA + 64 * 32);
    gload16(gB + go, lB);
    gload16(gB + go + (size_t)64 * K, lB + 64 * 32);
    __syncthreads();
    bf16x8 aF[4], bF[NR];
    #pragma unroll
    for (int m = 0; m < 4; ++m) aF[m] = *(const bf16x8*)&As[(wr * 64 + m * 16 + l15) * 32 + l16 * 8];
    #pragma unroll
    for (int n = 0; n < NR; ++n) bF[n] = *(const bf16x8*)&Bs[(wc * WCS + n * 16 + l15) * 32 + l16 * 8];
    #pragma unroll
    for (int m = 0; m < 4; ++m)
      #pragma unroll
      for (int n = 0; n < NR; ++n)
        acc[m][n] = __builtin_amdgcn_mfma_f32_16x16x32_bf16(aF[m], bF[n], acc[m][n], 0, 0, 0);
    __syncthreads();
  }

  #pragma unroll
  for (int m = 0; m < 4; ++m) {
    int row = bm * TM + wr * 64 + m * 16 + l16 * 4;
    #pragma unroll
    for (int n = 0; n < NR; ++n) {
      int col = bn * 128 + wc * WCS + n * 16 + l15;
      float bv;
      if (EPI == 0) bv = (col < 768) ? b0[col] : (col < 1536 ? b1[col - 768] : b2[col - 1536]);
      else          bv = b0[col];
      #pragma unroll
      for (int r = 0; r < 4; ++r) {
        float v = acc[m][n][r] + bv;
        size_t off = (size_t)(row + r) * N + col;
        if (EPI == 0) {
          outb[off] = f2bf(v);
        } else if (EPI == 1) {
          float g = 0.5f * v * (1.0f + erff(v * 0.70710678118654752f));  // exact GELU
          outb[off] = f2bf(g);
        } else {
          resid[off] += v;
        }
      }
    }
  }
}

// ---------------- flash attention, tiled block-causal mask, fused-QKV input ----------------
// grid (40 q-tiles reversed, B*H). 4 waves; wave owns 16 q rows. k-tiles of 64.
// tile skip if kpos0>qpos0 (block-uniform), triangular mask if equal.
__global__ __launch_bounds__(256) void attn_kernel(
    const u16* __restrict__ qkv, u16* __restrict__ yb)
{
  __shared__ __align__(16) u16 Ks[64 * 72];        // [key][hd], padded
  __shared__ __align__(16) u16 Vt[64 * 72];        // [hd][key], padded (transposed V)
  __shared__ __align__(16) u16 Ps[4 * 16 * 72];    // per-wave P buffer [16 q][64 key]
  const int qt = 39 - blockIdx.x;                  // heavy tiles dispatch first
  const int bh = blockIdx.y;
  const int b = bh / NH, h = bh - (bh / NH) * NH;
  const int tid = threadIdx.x;
  const int wave = tid >> 6, lane = tid & 63;
  const int l15 = lane & 15, l16 = lane >> 4;
  const size_t rb = (size_t)b * TT * LDQ + (size_t)h * HD;
  const int q0 = qt * 64;
  const int qpos0 = q0 & 255;

  bf16x8 qA0, qA1;
  {
    int qr = q0 + wave * 16 + l15;
    qA0 = *(const bf16x8*)&qkv[rb + (size_t)qr * LDQ + l16 * 8];
    qA1 = *(const bf16x8*)&qkv[rb + (size_t)qr * LDQ + 32 + l16 * 8];
  }
  f32x4 o[4];
  #pragma unroll
  for (int n = 0; n < 4; ++n) o[n] = f32x4{0.f, 0.f, 0.f, 0.f};
  float mrow[4] = {-1e30f, -1e30f, -1e30f, -1e30f};
  float lrow[4] = {0.f, 0.f, 0.f, 0.f};

  const int st = tid >> 3;           // 0..31 staging row
  const int sd = (tid & 7) * 8;      // 0..56 staging col
  const u16* kb = qkv + rb + 768;
  const u16* vb = qkv + rb + 1536;
  u16* psw = &Ps[wave * 16 * 72];

  // prefetch tile kt=0 (always valid) into regs
  bf16x8 kreg0 = *(const bf16x8*)&kb[(size_t)st * LDQ + sd];
  bf16x8 kreg1 = *(const bf16x8*)&kb[(size_t)(st + 32) * LDQ + sd];
  bf16x8 vreg0 = *(const bf16x8*)&vb[(size_t)st * LDQ + sd];
  bf16x8 vreg1 = *(const bf16x8*)&vb[(size_t)(st + 32) * LDQ + sd];

  for (int kt = 0; kt < TT / 64; ++kt) {
    int kpos0 = (kt * 64) & 255;
    if (kpos0 > qpos0) continue;     // fully masked tile
    __syncthreads();                 // prior tile's LDS reads complete
    *(bf16x8*)&Ks[st * 72 + sd] = kreg0;
    *(bf16x8*)&Ks[(st + 32) * 72 + sd] = kreg1;
    #pragma unroll
    for (int j = 0; j < 8; ++j) {
      int jj = (j + (sd >> 3)) & 7;
      Vt[(sd + jj) * 72 + st] = ((const u16*)&kreg0, (const u16*)&vreg0)[jj];
      Vt[(sd + jj) * 72 + st + 32] = ((const u16*)&vreg1)[jj];
    }
    // issue next valid tile's global loads (overlap with compute below)
    int kn = kt + 1;
    while (kn < TT / 64 && ((kn * 64) & 255) > qpos0) ++kn;
    if (kn < TT / 64) {
      kreg0 = *(const bf16x8*)&kb[(size_t)(kn * 64 + st) * LDQ + sd];
      kreg1 = *(const bf16x8*)&kb[(size_t)(kn * 64 + st + 32) * LDQ + sd];
      vreg0 = *(const bf16x8*)&vb[(size_t)(kn * 64 + st) * LDQ + sd];
      vreg1 = *(const bf16x8*)&vb[(size_t)(kn * 64 + st + 32) * LDQ + sd];
    }
    __syncthreads();

    // S = q @ k^T   (16q x 64k per wave)
    f32x4 s[4];
    __builtin_amdgcn_s_setprio(1);
    #pragma unroll
    for (int c = 0; c < 4; ++c) {
      bf16x8 k0 = *(const bf16x8*)&Ks[(c * 16 + l15) * 72 + l16 * 8];
      bf16x8 k1 = *(const bf16x8*)&Ks[(c * 16 + l15) * 72 + 32 + l16 * 8];
      f32x4 z = f32x4{0.f, 0.f, 0.f, 0.f};
      z = __builtin_amdgcn_mfma_f32_16x16x32_bf16(qA0, k0, z, 0, 0, 0);
      s[c] = __builtin_amdgcn_mfma_f32_16x16x32_bf16(qA1, k1, z, 0, 0, 0);
    }
    __builtin_amdgcn_s_setprio(0);
    const bool diag = (kpos0 == qpos0);
    #pragma unroll
    for (int c = 0; c < 4; ++c)
      #pragma unroll
      for (int r = 0; r < 4; ++r) {
        float sv = s[c][r] * 0.125f;             // 1/sqrt(64)
        if (diag && (c * 16 + l15) > (wave * 16 + l16 * 4 + r)) sv = -1e30f;
        s[c][r] = sv;
      }

    // online softmax per q-row (rows live on 16-lane groups)
    #pragma unroll
    for (int r = 0; r < 4; ++r) {
      float t = fmaxf(fmaxf(s[0][r], s[1][r]), fmaxf(s[2][r], s[3][r]));
      t = fmaxf(t, __shfl_xor(t, 1, 64));
      t = fmaxf(t, __shfl_xor(t, 2, 64));
      t = fmaxf(t, __shfl_xor(t, 4, 64));
      t = fmaxf(t, __shfl_xor(t, 8, 64));
      float mnew = fmaxf(mrow[r], t);
      float sf = __expf(mrow[r] - mnew);
      mrow[r] = mnew;
      lrow[r] *= sf;
      #pragma unroll
      for (int n = 0; n < 4; ++n) o[n][r] *= sf;
      float ts = 0.f;
      #pragma unroll
      for (int c = 0; c < 4; ++c) {
        float p = __expf(s[c][r] - mnew);        // masked -> 0
        s[c][r] = p;
        ts += p;
      }
      ts += __shfl_xor(ts, 1, 64);
      ts += __shfl_xor(ts, 2, 64);
      ts += __shfl_xor(ts, 4, 64);
      ts += __shfl_xor(ts, 8, 64);
      lrow[r] += ts;
      #pragma unroll
      for (int c = 0; c < 4; ++c)
        psw[(l16 * 4 + r) * 72 + c * 16 + l15] = f2bf(s[c][r]);
    }

    // O += P @ V  (contract over 64 keys)
    bf16x8 pA0 = *(const bf16x8*)&psw[l15 * 72 + l16 * 8];
    bf16x8 pA1 = *(const bf16x8*)&psw[l15 * 72 + 32 + l16 * 8];
    __builtin_amdgcn_s_setprio(1);
    #pragma unroll
    for (int n = 0; n < 4; ++n) {
      bf16x8 v0 = *(const bf16x8*)&Vt[(n * 16 + l15) * 72 + l16 * 8];
      bf16x8 v1 = *(const bf16x8*)&Vt[(n * 16 + l15) * 72 + 32 + l16 * 8];
      o[n] = __builtin_amdgcn_mfma_f32_16x16x32_bf16(pA0, v0, o[n], 0, 0, 0);
      o[n] = __builtin_amdgcn_mfma_f32_16x16x32_bf16(pA1, v1, o[n], 0, 0, 0);
    }
    __builtin_amdgcn_s_setprio(0);
  }

  #pragma unroll
  for (int r = 0; r < 4; ++r) {
    float invl = 1.0f / lrow[r];
    int row = q0 + wave * 16 + l16 * 4 + r;
    #pragma unroll
    for (int n = 0; n < 4; ++n) {
      int col = h * HD + n * 16 + l15;
      yb[(size_t)(b * TT + row) * TC + col] = f2bf(o[n][r] * invl);
    }
  }
}

// ---------------- host ----------------
extern "C" void kernel_launch(void* const* d_in, const int* in_sizes, int n_in,
                              void* d_out, int out_size, void* d_ws, size_t ws_size,
                              hipStream_t stream)
{
  (void)in_sizes; (void)n_in; (void)out_size; (void)ws_size;
  const float* IU = (const float*)d_in[0];
  const float* ID = (const float*)d_in[1];
  const float* IL = (const float*)d_in[2];
  const float* IR = (const float*)d_in[3];
  const float* IT = (const float*)d_in[4];
  const float* CM = (const float*)d_in[5];
  const float* CU = (const float*)d_in[6];
  const float* CD = (const float*)d_in[7];
  const float* CL = (const float*)d_in[8];
  const float* CR = (const float*)d_in[9];
  const float* POS = (const float*)d_in[10];
  const float* LN1W = (const float*)d_in[11];
  const float* LN1B = (const float*)d_in[12];
  const float* LN2W = (const float*)d_in[13];
  const float* LN2B = (const float*)d_in[14];
  const float* WQ = (const float*)d_in[15];
  const float* WK = (const float*)d_in[16];
  const float* WV = (const float*)d_in[17];
  const float* WP = (const float*)d_in[18];
  const float* BQ = (const float*)d_in[19];
  const float* BK = (const float*)d_in[20];
  const float* BV = (const float*)d_in[21];
  const float* BP = (const float*)d_in[22];
  const float* W1 = (const float*)d_in[23];
  const float* B1 = (const float*)d_in[24];
  const float* W2 = (const float*)d_in[25];
  const float* B2 = (const float*)d_in[26];

  float* x = (float*)d_out;
  char* ws = (char*)d_ws;
  // ws layout (bytes), total 53,477,376:
  u16* ws_wqkv = (u16*)(ws + 0);          // [2304][768] bf16
  u16* ws_wp   = (u16*)(ws + 3538944);    // [768][768]
  u16* ws_w1   = (u16*)(ws + 4718592);    // [3072][768]
  u16* ws_w2   = (u16*)(ws + 9437184);    // [768][3072]
  u16* ws_h    = (u16*)(ws + 14155776);   // [5120][768]
  u16* ws_qkv  = (u16*)(ws + 22020096);   // [5120][2304]
  u16* ws_y    = (u16*)(ws + 45613056);   // [5120][768]
  u16* ws_g    = ws_qkv;                  // [5120][3072] aliases qkv+y (dead by MLP1)

  embed_kernel<<<(NM * TC / 4) / 256, 256, 0, stream>>>(CM, CU, CD, CL, CR, IU, ID, IL, IR, IT, POS, x);

  const int SQ = 768 * 768;
  const int W1SL = 3072 * 768;
  for (int li = 0; li < NL; ++li) {
    conv_all_kernel<<<6912, 256, 0, stream>>>(
        WQ + (size_t)li * SQ, WK + (size_t)li * SQ, WV + (size_t)li * SQ,
        WP + (size_t)li * SQ, W1 + (size_t)li * W1SL, W2 + (size_t)li * W1SL,
        ws_wqkv, ws_wp, ws_w1, ws_w2);

    ln_kernel<<<NM, 256, 0, stream>>>(x, LN1W + li * TC, LN1B + li * TC, ws_h);
    gemm_kernel<0, 128><<<dim3(NM / 128, 2304 / 128), 256, 0, stream>>>(
        ws_h, ws_wqkv, BQ + li * TC, BK + li * TC, BV + li * TC, ws_qkv, nullptr, 768, 2304);
    attn_kernel<<<dim3(TT / 64, NB * NH), 256, 0, stream>>>(ws_qkv, ws_y);
    gemm_kernel<2, 64><<<dim3(NM / 64, 768 / 128), 256, 0, stream>>>(
        ws_y, ws_wp, BP + li * TC, nullptr, nullptr, nullptr, x, 768, 768);
    ln_kernel<<<NM, 256, 0, stream>>>(x, LN2W + li * TC, LN2B + li * TC, ws_h);
    gemm_kernel<1, 128><<<dim3(NM / 128, 3072 / 128), 256, 0, stream>>>(
        ws_h, ws_w1, B1 + (size_t)li * 3072, nullptr, nullptr, ws_g, nullptr, 768, 3072);
    gemm_kernel<2, 64><<<dim3(NM / 64, 768 / 128), 256, 0, stream>>>(
        ws_g, ws_w2, B2 + li * TC, nullptr, nullptr, nullptr, x, 3072, 768);
  }
}